// Round 17
// baseline (85.874 us; speedup 1.0000x reference)
//
#include <hip/hip_runtime.h>
#include <math.h>

// ---------------------------------------------------------------------------
// PinSageConv, round 17: R16 + 4-DEEP gather unroll (MLP x2 for the
// latency-bound random row reads; accumulation order preserved).
//   hist+cvt   : blocks <G bucket histogram || blocks >=G stream-convert
//                h->hb, qw->qwb, ww->wwb (f32->bf16 RNE)
//   scan_blk   : per-1024-chunk exclusive scan (raw 196 totals in partials)
//   part+gemm1 : blocks <G partition edges (inline total-scan);
//                blocks >=G gemm1 1 tile/block, A/B via global_load_lds
//   bsort_gather: block=bucket(32 rows): sort run into LDS, 4-deep gather
//   gemm2      : A(ph0)=hb, A(ph1)=z2, B=wwb -- global_load_lds; rownorm
// Edge payload eb: int2{ (dst&31)<<17 | src , w }  (src < 2^17)
// MFMA 16x16x32_bf16 (m89-verified); swapped (b,a) => lane&15 = out row.
// ---------------------------------------------------------------------------

typedef __attribute__((ext_vector_type(8))) short  short8;
typedef __attribute__((ext_vector_type(8))) __bf16 bf16x8;
typedef __attribute__((ext_vector_type(4))) float  f32x4;

#define MFMA16(a, b, c) __builtin_amdgcn_mfma_f32_16x16x32_bf16( \
    __builtin_bit_cast(bf16x8, (a)), __builtin_bit_cast(bf16x8, (b)), (c), 0, 0, 0)

#define EDGE_CAP 2048   // LDS edge buffer per 32-row bucket (mean ~384)

__device__ __forceinline__ ushort f2bf(float x) {            // RNE f32->bf16
    unsigned u = __float_as_uint(x);
    return (ushort)((u + 0x7fffu + ((u >> 16) & 1u)) >> 16);
}
__device__ __forceinline__ float bfhi(unsigned p) { return __uint_as_float(p & 0xffff0000u); }
__device__ __forceinline__ float bflo(unsigned p) { return __uint_as_float(p << 16); }

__device__ __forceinline__ short8 cvt8(float4 v0, float4 v1) {
    ushort t[8] = { f2bf(v0.x), f2bf(v0.y), f2bf(v0.z), f2bf(v0.w),
                    f2bf(v1.x), f2bf(v1.y), f2bf(v1.z), f2bf(v1.w) };
    return *(short8*)t;
}

// async 16B global->LDS copy; LDS dest wave-uniform base + lane*16 (m104)
__device__ __forceinline__ void gload16(const void* g, void* l) {
    __builtin_amdgcn_global_load_lds(
        (const __attribute__((address_space(1))) void*)g,
        (__attribute__((address_space(3))) void*)l, 16, 0, 0);
}

// ---------------- hist (blocks < G) || f32->bf16 cvt (blocks >= G) ---------
__global__ __launch_bounds__(512) void k_hist_cvt(const int* __restrict__ dst,
    int* __restrict__ hist, int nedges, int nb, int G,
    const float* __restrict__ h, const float* __restrict__ qw,
    const float* __restrict__ ww, ushort* __restrict__ hb,
    ushort* __restrict__ qwb, ushort* __restrict__ wwb, int n_src)
{
    const int tid = threadIdx.x;
    if ((int)blockIdx.x >= G) {
        const long Uh = (long)n_src * 16;
        const long Uq = 2048, Uw = 4096;
        const long u0 = (long)(blockIdx.x - G) * 512 + tid;
        const long stride = (long)(gridDim.x - G) * 512;
        for (long u = u0; u < Uh + Uq + Uw; u += stride) {
            const float* s; ushort* d; long i;
            if (u < Uh)            { s = h;  d = hb;  i = u; }
            else if (u < Uh + Uq)  { s = qw; d = qwb; i = u - Uh; }
            else                   { s = ww; d = wwb; i = u - Uh - Uq; }
            float4 a0 = *(const float4*)&s[i * 8];
            float4 a1 = *(const float4*)&s[i * 8 + 4];
            *(short8*)&d[i * 8] = cvt8(a0, a1);
        }
        return;
    }
    __shared__ int hl[2048];
    const int g = blockIdx.x;
    for (int i = tid; i < nb; i += 512) hl[i] = 0;
    __syncthreads();
    const int chunk = (nedges + G - 1) / G;
    const int e0 = g * chunk, e1 = min(e0 + chunk, nedges);
    for (int e = e0 + tid; e < e1; e += 512)
        atomicAdd(&hl[dst[e] >> 5], 1);
    __syncthreads();
    for (int i = tid; i < nb; i += 512) hist[i * G + g] = hl[i];
}

// ---------------- per-chunk exclusive scan over nb*G bins ------------------
__global__ __launch_bounds__(1024) void k_scan_blk(const int* __restrict__ counts,
    int* __restrict__ offs, int* __restrict__ partials, int n)
{
    __shared__ int wtot[16];
    const int tid = threadIdx.x, lane = tid & 63, wv = tid >> 6;
    const int idx = blockIdx.x * 1024 + tid;
    int v = (idx < n) ? counts[idx] : 0;
    int x = v;
    #pragma unroll
    for (int off = 1; off < 64; off <<= 1) {
        int y = __shfl_up(x, off);
        if (lane >= off) x += y;
    }
    if (lane == 63) wtot[wv] = x;
    __syncthreads();
    if (tid == 0) {
        int r = 0;
        #pragma unroll
        for (int q = 0; q < 16; ++q) { int t = wtot[q]; wtot[q] = r; r += t; }
    }
    __syncthreads();
    if (idx < n) offs[idx] = wtot[wv] + x - v;
    if (tid == 1023) partials[blockIdx.x] = wtot[15] + x;   // RAW totals
}

// ---------------- part (blocks < G) || async gemm1 (blocks >= G) -----------
__global__ __launch_bounds__(512) void k_part_gemm1(
    const int* __restrict__ src, const int* __restrict__ dst,
    const float* __restrict__ w, const int* __restrict__ binoff0,
    const int* __restrict__ partials, int2* __restrict__ eb,
    int nedges, int nb, int nbs, int G,
    const ushort* __restrict__ hb, const ushort* __restrict__ qwb,
    const float* __restrict__ qb, ushort* __restrict__ nout, int nrows)
{
    __shared__ __align__(16) ushort aL[128 * 128];   // gemm1 A  | part: cur
    __shared__ __align__(16) ushort bL[128 * 128];   // gemm1 B  | part: pscan
    __shared__ int wtmp[8];
    const int tid = threadIdx.x;

    if ((int)blockIdx.x < G) {
        int* cur   = (int*)aL;           // nb ints
        int* pscan = (int*)bL;           // nbs ints
        const int g = blockIdx.x;
        {
            const int lane = tid & 63, wv = tid >> 6;
            int v = (tid < nbs) ? partials[tid] : 0;
            int x = v;
            #pragma unroll
            for (int off = 1; off < 64; off <<= 1) {
                int y = __shfl_up(x, off);
                if (lane >= off) x += y;
            }
            if (lane == 63) wtmp[wv] = x;
            __syncthreads();
            if (tid == 0) {
                int r = 0;
                #pragma unroll
                for (int q = 0; q < 4; ++q) { int t = wtmp[q]; wtmp[q] = r; r += t; }
            }
            __syncthreads();
            if (tid < nbs) pscan[tid] = wtmp[wv] + x - v;
        }
        __syncthreads();
        for (int b = tid; b < nb; b += 512) {
            int i = b * G + g;
            cur[b] = binoff0[i] + pscan[i >> 10];
        }
        __syncthreads();
        const int chunk = (nedges + G - 1) / G;
        const int e0 = g * chunk, e1 = min(e0 + chunk, nedges);
        for (int e = e0 + tid; e < e1; e += 512) {
            int d = dst[e];
            int pos = atomicAdd(&cur[d >> 5], 1);            // LDS cursor
            eb[pos] = make_int2(((d & 31) << 17) | src[e], __float_as_int(w[e]));
        }
        return;
    }

    // ---- GEMM1: 1 tile, A+B via global_load_lds (linear LDS dest,
    //      pre-swizzled global source; read applies the same XOR)
    const int gb = blockIdx.x - G;
    const int rb = gb * 128;
    const int w_ = tid >> 6, l = tid & 63;
    const int lr = l & 15, lk = l >> 4;
    const int row = w_ * 16 + lr;

    #pragma unroll
    for (int i = 0; i < 4; ++i) {
        const int rl   = w_ * 16 + i * 4 + (l >> 4);   // local row 0..127
        const int slot = (l & 15) ^ (rl & 7);
        gload16(&qwb[rl * 128 + slot * 8],                 &bL[(w_ * 16 + i * 4) * 128]);
        gload16(&hb[(size_t)(rb + rl) * 128 + slot * 8],   &aL[(w_ * 16 + i * 4) * 128]);
    }
    __syncthreads();    // vmcnt(0) drain: all LDS writes landed

    short8 a[4];
    #pragma unroll
    for (int ks = 0; ks < 4; ++ks)
        a[ks] = *(const short8*)&aL[row * 128 + ((ks * 4 + lk) ^ (lr & 7)) * 8];

    f32x4 acc[8];
    #pragma unroll
    for (int nt = 0; nt < 8; ++nt) acc[nt] = (f32x4){0.f, 0.f, 0.f, 0.f};

    #pragma unroll
    for (int nt = 0; nt < 8; ++nt)
        #pragma unroll
        for (int ks = 0; ks < 4; ++ks) {
            short8 b = *(const short8*)&bL[(nt * 16 + lr) * 128 + ((ks * 4 + lk) ^ (lr & 7)) * 8];
            acc[nt] = MFMA16(b, a[ks], acc[nt]);   // swapped: lane&15 = row
        }

    const int gr = rb + row;
    if (gr < nrows) {
        #pragma unroll
        for (int nt = 0; nt < 8; ++nt) {
            float4 bv = *(const float4*)&qb[nt * 16 + lk * 4];
            ushort t[4];
            t[0] = f2bf(fmaxf(acc[nt][0] + bv.x, 0.f));
            t[1] = f2bf(fmaxf(acc[nt][1] + bv.y, 0.f));
            t[2] = f2bf(fmaxf(acc[nt][2] + bv.z, 0.f));
            t[3] = f2bf(fmaxf(acc[nt][3] + bv.w, 0.f));
            *(ushort4*)&nout[(size_t)gr * 128 + nt * 16 + lk * 4] = *(ushort4*)t;
        }
    }
}

// ---------------- bsort+gather: 32-row bucket, 256 thr, 4-deep MLP ---------
__global__ __launch_bounds__(256) void k_bsort_gather(const ushort* __restrict__ nsrc,
    const int2* __restrict__ eb, const int* __restrict__ binoff0,
    const int* __restrict__ partials, ushort* __restrict__ z2,
    int ndst, int nedges, int G, int NB, int nbs)
{
    __shared__ int2 els[EDGE_CAP];    // 16 KB sorted edge run
    __shared__ int  pscan[256];
    __shared__ int  base[33];
    __shared__ int  cur[32];
    __shared__ int  wtmp[4];
    const int b = blockIdx.x, tid = threadIdx.x;

    {
        const int lane = tid & 63, wv = tid >> 6;
        int v = (tid < nbs) ? partials[tid] : 0;
        int x = v;
        #pragma unroll
        for (int off = 1; off < 64; off <<= 1) {
            int y = __shfl_up(x, off);
            if (lane >= off) x += y;
        }
        if (lane == 63) wtmp[wv] = x;
        __syncthreads();
        if (tid == 0) {
            int r = 0;
            #pragma unroll
            for (int q = 0; q < 4; ++q) { int t = wtmp[q]; wtmp[q] = r; r += t; }
        }
        __syncthreads();
        if (tid < nbs) pscan[tid] = wtmp[wv] + x - v;
    }
    if (tid < 32) cur[tid] = 0;
    __syncthreads();

    const int i0 = b * G;
    const int j0 = binoff0[i0] + pscan[i0 >> 10];
    int j1 = nedges;
    if (b != NB - 1) {
        int i1 = (b + 1) * G;
        j1 = binoff0[i1] + pscan[i1 >> 10];
    }
    const int cnt_e = j1 - j0;

    for (int j = j0 + tid; j < j1; j += 256)
        atomicAdd(&cur[eb[j].x >> 17], 1);
    __syncthreads();

    if (tid < 64) {                    // wave 0: exclusive scan of 32 counters
        int a = (tid < 32) ? cur[tid] : 0;
        int x = a;
        #pragma unroll
        for (int off = 1; off < 64; off <<= 1) {
            int y = __shfl_up(x, off);
            if (tid >= off) x += y;
        }
        if (tid < 32) {
            base[tid] = x - a;
            cur[tid]  = x - a;
        }
        if (tid == 31) base[32] = x;
    }
    __syncthreads();

    const int wv = tid >> 6, lane = tid & 63;   // 4 waves
    const int g = lane >> 4, s = lane & 15;

    if (cnt_e <= EDGE_CAP) {
        for (int j = j0 + tid; j < j1; j += 256) {
            int2 e = eb[j];
            int pos = atomicAdd(&cur[e.x >> 17], 1);
            els[pos] = make_int2(e.x & 0x1FFFF, e.y);
        }
        __syncthreads();

        // gather: wave wv handles local rows wv, wv+4, ...; group g walks
        // edges 4-deep (j, j+4, j+8, j+12 in flight simultaneously).
        for (int r = wv; r < 32; r += 4) {
            int gr = b * 32 + r;
            if (gr >= ndst) break;
            const int ja = base[r], jb = base[r + 1];
            float acc[8] = {0.f,0.f,0.f,0.f,0.f,0.f,0.f,0.f};
            float ws = 0.f;
            for (int j = ja + g; j < jb; j += 16) {
                int2  e[4];
                float we[4];
                short8 rv[4];
                #pragma unroll
                for (int k = 0; k < 4; ++k) {
                    bool ok = (j + k * 4 < jb);
                    e[k]  = ok ? els[j + k * 4] : els[j];
                    we[k] = ok ? __int_as_float(e[k].y) : 0.f;
                }
                #pragma unroll
                for (int k = 0; k < 4; ++k)
                    rv[k] = *(const short8*)&nsrc[(size_t)e[k].x * 128 + s * 8];
                #pragma unroll
                for (int k = 0; k < 4; ++k) {
                    uint4 p = __builtin_bit_cast(uint4, rv[k]);
                    acc[0] = fmaf(bflo(p.x), we[k], acc[0]);
                    acc[1] = fmaf(bfhi(p.x), we[k], acc[1]);
                    acc[2] = fmaf(bflo(p.y), we[k], acc[2]);
                    acc[3] = fmaf(bfhi(p.y), we[k], acc[3]);
                    acc[4] = fmaf(bflo(p.z), we[k], acc[4]);
                    acc[5] = fmaf(bfhi(p.z), we[k], acc[5]);
                    acc[6] = fmaf(bflo(p.w), we[k], acc[6]);
                    acc[7] = fmaf(bfhi(p.w), we[k], acc[7]);
                    ws += we[k];
                }
            }
            #pragma unroll
            for (int i = 0; i < 8; ++i) {
                acc[i] += __shfl_xor(acc[i], 16);
                acc[i] += __shfl_xor(acc[i], 32);
            }
            ws += __shfl_xor(ws, 16);
            ws += __shfl_xor(ws, 32);
            if (g == 0) {
                float inv = 1.f / fmaxf(ws, 1.f);
                ushort t8[8];
                #pragma unroll
                for (int i = 0; i < 8; ++i) t8[i] = f2bf(acc[i] * inv);
                *(short8*)&z2[(size_t)gr * 128 + s * 8] = *(short8*)t8;
            }
        }
    } else {
        // fallback (never triggers for this input; correctness only)
        for (int r = wv; r < 32; r += 4) {
            int gr = b * 32 + r;
            if (gr >= ndst) break;
            float acc[8] = {0.f,0.f,0.f,0.f,0.f,0.f,0.f,0.f};
            float ws = 0.f;
            for (int j = j0 + g; j < j1; j += 4) {
                int2 e = eb[j];
                if ((e.x >> 17) != r) continue;
                float we = __int_as_float(e.y);
                short8 rv = *(const short8*)&nsrc[(size_t)(e.x & 0x1FFFF) * 128 + s * 8];
                uint4 p = __builtin_bit_cast(uint4, rv);
                acc[0] = fmaf(bflo(p.x), we, acc[0]);
                acc[1] = fmaf(bfhi(p.x), we, acc[1]);
                acc[2] = fmaf(bflo(p.y), we, acc[2]);
                acc[3] = fmaf(bfhi(p.y), we, acc[3]);
                acc[4] = fmaf(bflo(p.z), we, acc[4]);
                acc[5] = fmaf(bfhi(p.z), we, acc[5]);
                acc[6] = fmaf(bflo(p.w), we, acc[6]);
                acc[7] = fmaf(bfhi(p.w), we, acc[7]);
                ws += we;
            }
            #pragma unroll
            for (int i = 0; i < 8; ++i) {
                acc[i] += __shfl_xor(acc[i], 16);
                acc[i] += __shfl_xor(acc[i], 32);
            }
            ws += __shfl_xor(ws, 16);
            ws += __shfl_xor(ws, 32);
            if (g == 0) {
                float inv = 1.f / fmaxf(ws, 1.f);
                ushort t8[8];
                #pragma unroll
                for (int i = 0; i < 8; ++i) t8[i] = f2bf(acc[i] * inv);
                *(short8*)&z2[(size_t)gr * 128 + s * 8] = *(short8*)t8;
            }
        }
    }
}

// ---------------- GEMM2 + rownorm: async-staged, 2 K-phases ----------------
__global__ __launch_bounds__(512) void k_gemm2(const ushort* __restrict__ hb,
    const ushort* __restrict__ z2, const ushort* __restrict__ wwb,
    const float* __restrict__ wb, float* __restrict__ out, int nrows)
{
    __shared__ __align__(16) ushort aL[128 * 128];
    __shared__ __align__(16) ushort bL[128 * 128];
    const int tid = threadIdx.x;
    const int rb  = blockIdx.x * 128;

    const int w = tid >> 6, l = tid & 63;
    const int lr = l & 15, lk = l >> 4;
    const int row = w * 16 + lr;

    f32x4 acc[8];
    #pragma unroll
    for (int nt = 0; nt < 8; ++nt) acc[nt] = (f32x4){0.f, 0.f, 0.f, 0.f};

    #pragma unroll
    for (int ph = 0; ph < 2; ++ph) {
        if (ph) __syncthreads();       // prior MFMA reads done before overwrite
        const ushort* As = ph ? z2 : hb;
        #pragma unroll
        for (int i = 0; i < 4; ++i) {
            const int rl   = w * 16 + i * 4 + (l >> 4);
            const int slot = (l & 15) ^ (rl & 7);
            gload16(&wwb[rl * 256 + ph * 128 + slot * 8],     &bL[(w * 16 + i * 4) * 128]);
            gload16(&As[(size_t)(rb + rl) * 128 + slot * 8],  &aL[(w * 16 + i * 4) * 128]);
        }
        __syncthreads();

        short8 a[4];
        #pragma unroll
        for (int ks = 0; ks < 4; ++ks)
            a[ks] = *(const short8*)&aL[row * 128 + ((ks * 4 + lk) ^ (lr & 7)) * 8];

        #pragma unroll
        for (int nt = 0; nt < 8; ++nt)
            #pragma unroll
            for (int ks = 0; ks < 4; ++ks) {
                short8 b = *(const short8*)&bL[(nt * 16 + lr) * 128 + ((ks * 4 + lk) ^ (lr & 7)) * 8];
                acc[nt] = MFMA16(b, a[ks], acc[nt]);
            }
    }

    float val[8][4];
    float ss = 0.f;
    #pragma unroll
    for (int nt = 0; nt < 8; ++nt) {
        float4 bv = *(const float4*)&wb[nt * 16 + lk * 4];
        #pragma unroll
        for (int v = 0; v < 4; ++v) {
            float x = acc[nt][v] + ((const float*)&bv)[v];
            x = fmaxf(x, 0.f);
            val[nt][v] = x;
            ss = fmaf(x, x, ss);
        }
    }
    ss += __shfl_xor(ss, 16);
    ss += __shfl_xor(ss, 32);
    float nr = sqrtf(ss);
    nr = (nr == 0.f) ? 1.f : nr;
    float inv = 1.f / nr;

    const int gr = rb + row;
    if (gr < nrows) {
        #pragma unroll
        for (int nt = 0; nt < 8; ++nt) {
            float4 o;
            o.x = val[nt][0] * inv; o.y = val[nt][1] * inv;
            o.z = val[nt][2] * inv; o.w = val[nt][3] * inv;
            *(float4*)&out[(size_t)gr * 128 + nt * 16 + lk * 4] = o;
        }
    }
}

// ---------------------------------------------------------------------------
extern "C" void kernel_launch(void* const* d_in, const int* in_sizes, int n_in,
                              void* d_out, int out_size, void* d_ws, size_t ws_size,
                              hipStream_t stream)
{
    const float* h   = (const float*)d_in[0];
    const float* wts = (const float*)d_in[1];
    const int*   src = (const int*)d_in[2];
    const int*   dst = (const int*)d_in[3];
    const float* qw  = (const float*)d_in[5];
    const float* qb  = (const float*)d_in[6];
    const float* www = (const float*)d_in[7];
    const float* wb  = (const float*)d_in[8];
    float* out = (float*)d_out;

    const int n_src   = in_sizes[0] / 128;
    const int n_edges = in_sizes[1];
    const int n_dst   = out_size / 128;

    const int G  = 128;                           // partition / hist blocks
    const int NB = (n_dst + 31) / 32;             // buckets of 32 dst rows (1563)
    const int NBINS = NB * G;                     // bin table (200064)
    const int nbs = (NBINS + 1023) / 1024;        // 196 (<=256 required)

    // workspace layout (all segment sizes even -> 16B alignment preserved)
    ushort* nbuf    = (ushort*)d_ws;                         // n_src*128 bf16
    ushort* z2      = nbuf + (size_t)n_src * 128;            // n_dst*128 bf16
    ushort* hb      = z2 + (size_t)n_dst * 128;              // n_src*128 bf16
    ushort* qwb     = hb + (size_t)n_src * 128;              // 16384 bf16
    ushort* wwb     = qwb + 16384;                           // 32768 bf16
    int2*   eb      = (int2*)(wwb + 32768);                  // n_edges int2
    int*    hist    = (int*)(eb + n_edges);                  // NBINS
    int*    binoff0 = hist + NBINS;                          // NBINS
    int*    parts   = binoff0 + NBINS;                       // <= 256 (raw totals)

    const int CVT = 768;                          // cvt blocks (one pass w/ hist)
    k_hist_cvt<<<G + CVT, 512, 0, stream>>>(dst, hist, n_edges, NB, G,
                                            h, qw, www, hb, qwb, wwb, n_src);

    k_scan_blk<<<nbs, 1024, 0, stream>>>(hist, binoff0, parts, NBINS);

    const int t1 = (n_src + 127) / 128;           // 782 gemm1 tiles/blocks
    k_part_gemm1<<<G + t1, 512, 0, stream>>>(src, dst, wts, binoff0, parts, eb,
                                             n_edges, NB, nbs, G,
                                             hb, qwb, qb, nbuf, n_src);

    k_bsort_gather<<<NB, 256, 0, stream>>>(nbuf, eb, binoff0, parts, z2,
                                           n_dst, n_edges, G, NB, nbs);

    const int t2 = (n_dst + 127) / 128;
    k_gemm2<<<t2, 512, 0, stream>>>(hb, z2, wwb, wb, out, n_dst);
}

// Round 18
// 83.656 us; speedup vs baseline: 1.0265x; 1.0265x over previous
//
#include <hip/hip_runtime.h>
#include <math.h>

// ---------------------------------------------------------------------------
// PinSageConv, round 18: REVERT to R16 exactly (best measured: 84.4us).
// R17's 4-deep gather unroll was neutral-negative (85.9) -> gather is at its
// latency floor with 2-deep; restoring the best variant.
//   hist+cvt   : blocks <G bucket histogram || blocks >=G stream-convert
//                h->hb, qw->qwb, ww->wwb (f32->bf16 RNE)
//   scan_blk   : per-1024-chunk exclusive scan (raw 196 totals in partials)
//   part+gemm1 : blocks <G partition edges (inline total-scan);
//                blocks >=G gemm1 1 tile/block, A/B via global_load_lds
//   bsort_gather: block=bucket(32 rows): sort run into LDS, 2-deep gather
//   gemm2      : A(ph0)=hb, A(ph1)=z2, B=wwb -- global_load_lds; rownorm
// Edge payload eb: int2{ (dst&31)<<17 | src , w }  (src < 2^17)
// MFMA 16x16x32_bf16 (m89-verified); swapped (b,a) => lane&15 = out row.
// ---------------------------------------------------------------------------

typedef __attribute__((ext_vector_type(8))) short  short8;
typedef __attribute__((ext_vector_type(8))) __bf16 bf16x8;
typedef __attribute__((ext_vector_type(4))) float  f32x4;

#define MFMA16(a, b, c) __builtin_amdgcn_mfma_f32_16x16x32_bf16( \
    __builtin_bit_cast(bf16x8, (a)), __builtin_bit_cast(bf16x8, (b)), (c), 0, 0, 0)

#define EDGE_CAP 2048   // LDS edge buffer per 32-row bucket (mean ~384)

__device__ __forceinline__ ushort f2bf(float x) {            // RNE f32->bf16
    unsigned u = __float_as_uint(x);
    return (ushort)((u + 0x7fffu + ((u >> 16) & 1u)) >> 16);
}
__device__ __forceinline__ float bfhi(unsigned p) { return __uint_as_float(p & 0xffff0000u); }
__device__ __forceinline__ float bflo(unsigned p) { return __uint_as_float(p << 16); }

__device__ __forceinline__ short8 cvt8(float4 v0, float4 v1) {
    ushort t[8] = { f2bf(v0.x), f2bf(v0.y), f2bf(v0.z), f2bf(v0.w),
                    f2bf(v1.x), f2bf(v1.y), f2bf(v1.z), f2bf(v1.w) };
    return *(short8*)t;
}

// async 16B global->LDS copy; LDS dest wave-uniform base + lane*16 (m104)
__device__ __forceinline__ void gload16(const void* g, void* l) {
    __builtin_amdgcn_global_load_lds(
        (const __attribute__((address_space(1))) void*)g,
        (__attribute__((address_space(3))) void*)l, 16, 0, 0);
}

// ---------------- hist (blocks < G) || f32->bf16 cvt (blocks >= G) ---------
__global__ __launch_bounds__(512) void k_hist_cvt(const int* __restrict__ dst,
    int* __restrict__ hist, int nedges, int nb, int G,
    const float* __restrict__ h, const float* __restrict__ qw,
    const float* __restrict__ ww, ushort* __restrict__ hb,
    ushort* __restrict__ qwb, ushort* __restrict__ wwb, int n_src)
{
    const int tid = threadIdx.x;
    if ((int)blockIdx.x >= G) {
        // stream-convert in 8-float units
        const long Uh = (long)n_src * 16;
        const long Uq = 2048, Uw = 4096;
        const long u0 = (long)(blockIdx.x - G) * 512 + tid;
        const long stride = (long)(gridDim.x - G) * 512;
        for (long u = u0; u < Uh + Uq + Uw; u += stride) {
            const float* s; ushort* d; long i;
            if (u < Uh)            { s = h;  d = hb;  i = u; }
            else if (u < Uh + Uq)  { s = qw; d = qwb; i = u - Uh; }
            else                   { s = ww; d = wwb; i = u - Uh - Uq; }
            float4 a0 = *(const float4*)&s[i * 8];
            float4 a1 = *(const float4*)&s[i * 8 + 4];
            *(short8*)&d[i * 8] = cvt8(a0, a1);
        }
        return;
    }
    __shared__ int hl[2048];
    const int g = blockIdx.x;
    for (int i = tid; i < nb; i += 512) hl[i] = 0;
    __syncthreads();
    const int chunk = (nedges + G - 1) / G;
    const int e0 = g * chunk, e1 = min(e0 + chunk, nedges);
    for (int e = e0 + tid; e < e1; e += 512)
        atomicAdd(&hl[dst[e] >> 5], 1);
    __syncthreads();
    for (int i = tid; i < nb; i += 512) hist[i * G + g] = hl[i];
}

// ---------------- per-chunk exclusive scan over nb*G bins ------------------
__global__ __launch_bounds__(1024) void k_scan_blk(const int* __restrict__ counts,
    int* __restrict__ offs, int* __restrict__ partials, int n)
{
    __shared__ int wtot[16];
    const int tid = threadIdx.x, lane = tid & 63, wv = tid >> 6;
    const int idx = blockIdx.x * 1024 + tid;
    int v = (idx < n) ? counts[idx] : 0;
    int x = v;
    #pragma unroll
    for (int off = 1; off < 64; off <<= 1) {
        int y = __shfl_up(x, off);
        if (lane >= off) x += y;
    }
    if (lane == 63) wtot[wv] = x;
    __syncthreads();
    if (tid == 0) {
        int r = 0;
        #pragma unroll
        for (int q = 0; q < 16; ++q) { int t = wtot[q]; wtot[q] = r; r += t; }
    }
    __syncthreads();
    if (idx < n) offs[idx] = wtot[wv] + x - v;
    if (tid == 1023) partials[blockIdx.x] = wtot[15] + x;   // RAW totals
}

// ---------------- part (blocks < G) || async gemm1 (blocks >= G) -----------
__global__ __launch_bounds__(512) void k_part_gemm1(
    const int* __restrict__ src, const int* __restrict__ dst,
    const float* __restrict__ w, const int* __restrict__ binoff0,
    const int* __restrict__ partials, int2* __restrict__ eb,
    int nedges, int nb, int nbs, int G,
    const ushort* __restrict__ hb, const ushort* __restrict__ qwb,
    const float* __restrict__ qb, ushort* __restrict__ nout, int nrows)
{
    __shared__ __align__(16) ushort aL[128 * 128];   // gemm1 A  | part: cur
    __shared__ __align__(16) ushort bL[128 * 128];   // gemm1 B  | part: pscan
    __shared__ int wtmp[8];
    const int tid = threadIdx.x;

    if ((int)blockIdx.x < G) {
        // ---- partition path
        int* cur   = (int*)aL;           // nb ints
        int* pscan = (int*)bL;           // nbs ints
        const int g = blockIdx.x;
        {
            const int lane = tid & 63, wv = tid >> 6;
            int v = (tid < nbs) ? partials[tid] : 0;
            int x = v;
            #pragma unroll
            for (int off = 1; off < 64; off <<= 1) {
                int y = __shfl_up(x, off);
                if (lane >= off) x += y;
            }
            if (lane == 63) wtmp[wv] = x;
            __syncthreads();
            if (tid == 0) {
                int r = 0;
                #pragma unroll
                for (int q = 0; q < 4; ++q) { int t = wtmp[q]; wtmp[q] = r; r += t; }
            }
            __syncthreads();
            if (tid < nbs) pscan[tid] = wtmp[wv] + x - v;
        }
        __syncthreads();
        for (int b = tid; b < nb; b += 512) {
            int i = b * G + g;
            cur[b] = binoff0[i] + pscan[i >> 10];
        }
        __syncthreads();
        const int chunk = (nedges + G - 1) / G;
        const int e0 = g * chunk, e1 = min(e0 + chunk, nedges);
        for (int e = e0 + tid; e < e1; e += 512) {
            int d = dst[e];
            int pos = atomicAdd(&cur[d >> 5], 1);            // LDS cursor
            eb[pos] = make_int2(((d & 31) << 17) | src[e], __float_as_int(w[e]));
        }
        return;
    }

    // ---- GEMM1: 1 tile, A+B staged via global_load_lds (linear LDS,
    //      pre-swizzled global source; read applies the same XOR)
    const int gb = blockIdx.x - G;
    const int rb = gb * 128;
    const int w_ = tid >> 6, l = tid & 63;
    const int lr = l & 15, lk = l >> 4;
    const int row = w_ * 16 + lr;

    #pragma unroll
    for (int i = 0; i < 4; ++i) {
        const int rl   = w_ * 16 + i * 4 + (l >> 4);   // local row 0..127
        const int slot = (l & 15) ^ (rl & 7);
        gload16(&qwb[rl * 128 + slot * 8],                 &bL[(w_ * 16 + i * 4) * 128]);
        gload16(&hb[(size_t)(rb + rl) * 128 + slot * 8],   &aL[(w_ * 16 + i * 4) * 128]);
    }
    __syncthreads();    // vmcnt(0) drain: all LDS writes landed

    short8 a[4];
    #pragma unroll
    for (int ks = 0; ks < 4; ++ks)
        a[ks] = *(const short8*)&aL[row * 128 + ((ks * 4 + lk) ^ (lr & 7)) * 8];

    f32x4 acc[8];
    #pragma unroll
    for (int nt = 0; nt < 8; ++nt) acc[nt] = (f32x4){0.f, 0.f, 0.f, 0.f};

    #pragma unroll
    for (int nt = 0; nt < 8; ++nt)
        #pragma unroll
        for (int ks = 0; ks < 4; ++ks) {
            short8 b = *(const short8*)&bL[(nt * 16 + lr) * 128 + ((ks * 4 + lk) ^ (lr & 7)) * 8];
            acc[nt] = MFMA16(b, a[ks], acc[nt]);   // swapped: lane&15 = row
        }

    const int gr = rb + row;
    if (gr < nrows) {
        #pragma unroll
        for (int nt = 0; nt < 8; ++nt) {
            float4 bv = *(const float4*)&qb[nt * 16 + lk * 4];
            ushort t[4];
            t[0] = f2bf(fmaxf(acc[nt][0] + bv.x, 0.f));
            t[1] = f2bf(fmaxf(acc[nt][1] + bv.y, 0.f));
            t[2] = f2bf(fmaxf(acc[nt][2] + bv.z, 0.f));
            t[3] = f2bf(fmaxf(acc[nt][3] + bv.w, 0.f));
            *(ushort4*)&nout[(size_t)gr * 128 + nt * 16 + lk * 4] = *(ushort4*)t;
        }
    }
}

// ---------------- bsort+gather: block = bucket of 32 rows, 256 thr ---------
__global__ __launch_bounds__(256) void k_bsort_gather(const ushort* __restrict__ nsrc,
    const int2* __restrict__ eb, const int* __restrict__ binoff0,
    const int* __restrict__ partials, ushort* __restrict__ z2,
    int ndst, int nedges, int G, int NB, int nbs)
{
    __shared__ int2 els[EDGE_CAP];    // 16 KB sorted edge run
    __shared__ int  pscan[256];
    __shared__ int  base[33];
    __shared__ int  cur[32];
    __shared__ int  wtmp[4];
    const int b = blockIdx.x, tid = threadIdx.x;

    {
        const int lane = tid & 63, wv = tid >> 6;
        int v = (tid < nbs) ? partials[tid] : 0;
        int x = v;
        #pragma unroll
        for (int off = 1; off < 64; off <<= 1) {
            int y = __shfl_up(x, off);
            if (lane >= off) x += y;
        }
        if (lane == 63) wtmp[wv] = x;
        __syncthreads();
        if (tid == 0) {
            int r = 0;
            #pragma unroll
            for (int q = 0; q < 4; ++q) { int t = wtmp[q]; wtmp[q] = r; r += t; }
        }
        __syncthreads();
        if (tid < nbs) pscan[tid] = wtmp[wv] + x - v;
    }
    if (tid < 32) cur[tid] = 0;
    __syncthreads();

    const int i0 = b * G;
    const int j0 = binoff0[i0] + pscan[i0 >> 10];
    int j1 = nedges;
    if (b != NB - 1) {
        int i1 = (b + 1) * G;
        j1 = binoff0[i1] + pscan[i1 >> 10];
    }
    const int cnt_e = j1 - j0;

    for (int j = j0 + tid; j < j1; j += 256)
        atomicAdd(&cur[eb[j].x >> 17], 1);
    __syncthreads();

    if (tid < 64) {                    // wave 0: exclusive scan of 32 counters
        int a = (tid < 32) ? cur[tid] : 0;
        int x = a;
        #pragma unroll
        for (int off = 1; off < 64; off <<= 1) {
            int y = __shfl_up(x, off);
            if (tid >= off) x += y;
        }
        if (tid < 32) {
            base[tid] = x - a;
            cur[tid]  = x - a;
        }
        if (tid == 31) base[32] = x;
    }
    __syncthreads();

    const int wv = tid >> 6, lane = tid & 63;   // 4 waves
    const int g = lane >> 4, s = lane & 15;

    if (cnt_e <= EDGE_CAP) {
        for (int j = j0 + tid; j < j1; j += 256) {
            int2 e = eb[j];
            int pos = atomicAdd(&cur[e.x >> 17], 1);
            els[pos] = make_int2(e.x & 0x1FFFF, e.y);
        }
        __syncthreads();

        for (int r = wv; r < 32; r += 4) {
            int gr = b * 32 + r;
            if (gr >= ndst) break;
            const int ja = base[r], jb = base[r + 1];
            float acc[8] = {0.f,0.f,0.f,0.f,0.f,0.f,0.f,0.f};
            float ws = 0.f;
            for (int j = ja + g; j < jb; j += 8) {
                int2 e1 = els[j];
                bool has2 = (j + 4 < jb);
                int2 e2 = has2 ? els[j + 4] : e1;
                float w1 = __int_as_float(e1.y);
                float w2 = has2 ? __int_as_float(e2.y) : 0.f;
                short8 r1 = *(const short8*)&nsrc[(size_t)e1.x * 128 + s * 8];
                short8 r2 = *(const short8*)&nsrc[(size_t)e2.x * 128 + s * 8];
                uint4 p1 = __builtin_bit_cast(uint4, r1);
                uint4 p2 = __builtin_bit_cast(uint4, r2);
                acc[0] = fmaf(bflo(p1.x), w1, acc[0]);
                acc[1] = fmaf(bfhi(p1.x), w1, acc[1]);
                acc[2] = fmaf(bflo(p1.y), w1, acc[2]);
                acc[3] = fmaf(bfhi(p1.y), w1, acc[3]);
                acc[4] = fmaf(bflo(p1.z), w1, acc[4]);
                acc[5] = fmaf(bfhi(p1.z), w1, acc[5]);
                acc[6] = fmaf(bflo(p1.w), w1, acc[6]);
                acc[7] = fmaf(bfhi(p1.w), w1, acc[7]);
                acc[0] = fmaf(bflo(p2.x), w2, acc[0]);
                acc[1] = fmaf(bfhi(p2.x), w2, acc[1]);
                acc[2] = fmaf(bflo(p2.y), w2, acc[2]);
                acc[3] = fmaf(bfhi(p2.y), w2, acc[3]);
                acc[4] = fmaf(bflo(p2.z), w2, acc[4]);
                acc[5] = fmaf(bfhi(p2.z), w2, acc[5]);
                acc[6] = fmaf(bflo(p2.w), w2, acc[6]);
                acc[7] = fmaf(bfhi(p2.w), w2, acc[7]);
                ws += w1 + w2;
            }
            #pragma unroll
            for (int i = 0; i < 8; ++i) {
                acc[i] += __shfl_xor(acc[i], 16);
                acc[i] += __shfl_xor(acc[i], 32);
            }
            ws += __shfl_xor(ws, 16);
            ws += __shfl_xor(ws, 32);
            if (g == 0) {
                float inv = 1.f / fmaxf(ws, 1.f);
                ushort t8[8];
                #pragma unroll
                for (int i = 0; i < 8; ++i) t8[i] = f2bf(acc[i] * inv);
                *(short8*)&z2[(size_t)gr * 128 + s * 8] = *(short8*)t8;
            }
        }
    } else {
        // fallback (never triggers for this input; correctness only)
        for (int r = wv; r < 32; r += 4) {
            int gr = b * 32 + r;
            if (gr >= ndst) break;
            float acc[8] = {0.f,0.f,0.f,0.f,0.f,0.f,0.f,0.f};
            float ws = 0.f;
            for (int j = j0 + g; j < j1; j += 4) {
                int2 e = eb[j];
                if ((e.x >> 17) != r) continue;
                float we = __int_as_float(e.y);
                short8 rv = *(const short8*)&nsrc[(size_t)(e.x & 0x1FFFF) * 128 + s * 8];
                uint4 p = __builtin_bit_cast(uint4, rv);
                acc[0] = fmaf(bflo(p.x), we, acc[0]);
                acc[1] = fmaf(bfhi(p.x), we, acc[1]);
                acc[2] = fmaf(bflo(p.y), we, acc[2]);
                acc[3] = fmaf(bfhi(p.y), we, acc[3]);
                acc[4] = fmaf(bflo(p.z), we, acc[4]);
                acc[5] = fmaf(bfhi(p.z), we, acc[5]);
                acc[6] = fmaf(bflo(p.w), we, acc[6]);
                acc[7] = fmaf(bfhi(p.w), we, acc[7]);
                ws += we;
            }
            #pragma unroll
            for (int i = 0; i < 8; ++i) {
                acc[i] += __shfl_xor(acc[i], 16);
                acc[i] += __shfl_xor(acc[i], 32);
            }
            ws += __shfl_xor(ws, 16);
            ws += __shfl_xor(ws, 32);
            if (g == 0) {
                float inv = 1.f / fmaxf(ws, 1.f);
                ushort t8[8];
                #pragma unroll
                for (int i = 0; i < 8; ++i) t8[i] = f2bf(acc[i] * inv);
                *(short8*)&z2[(size_t)gr * 128 + s * 8] = *(short8*)t8;
            }
        }
    }
}

// ---------------- GEMM2 + rownorm: async-staged, 2 K-phases ----------------
__global__ __launch_bounds__(512) void k_gemm2(const ushort* __restrict__ hb,
    const ushort* __restrict__ z2, const ushort* __restrict__ wwb,
    const float* __restrict__ wb, float* __restrict__ out, int nrows)
{
    __shared__ __align__(16) ushort aL[128 * 128];
    __shared__ __align__(16) ushort bL[128 * 128];
    const int tid = threadIdx.x;
    const int rb  = blockIdx.x * 128;

    const int w = tid >> 6, l = tid & 63;
    const int lr = l & 15, lk = l >> 4;
    const int row = w * 16 + lr;

    f32x4 acc[8];
    #pragma unroll
    for (int nt = 0; nt < 8; ++nt) acc[nt] = (f32x4){0.f, 0.f, 0.f, 0.f};

    #pragma unroll
    for (int ph = 0; ph < 2; ++ph) {
        if (ph) __syncthreads();       // prior MFMA reads done before overwrite
        const ushort* As = ph ? z2 : hb;
        #pragma unroll
        for (int i = 0; i < 4; ++i) {
            const int rl   = w * 16 + i * 4 + (l >> 4);
            const int slot = (l & 15) ^ (rl & 7);
            gload16(&wwb[rl * 256 + ph * 128 + slot * 8],     &bL[(w * 16 + i * 4) * 128]);
            gload16(&As[(size_t)(rb + rl) * 128 + slot * 8],  &aL[(w * 16 + i * 4) * 128]);
        }
        __syncthreads();

        short8 a[4];
        #pragma unroll
        for (int ks = 0; ks < 4; ++ks)
            a[ks] = *(const short8*)&aL[row * 128 + ((ks * 4 + lk) ^ (lr & 7)) * 8];

        #pragma unroll
        for (int nt = 0; nt < 8; ++nt)
            #pragma unroll
            for (int ks = 0; ks < 4; ++ks) {
                short8 b = *(const short8*)&bL[(nt * 16 + lr) * 128 + ((ks * 4 + lk) ^ (lr & 7)) * 8];
                acc[nt] = MFMA16(b, a[ks], acc[nt]);
            }
    }

    float val[8][4];
    float ss = 0.f;
    #pragma unroll
    for (int nt = 0; nt < 8; ++nt) {
        float4 bv = *(const float4*)&wb[nt * 16 + lk * 4];
        #pragma unroll
        for (int v = 0; v < 4; ++v) {
            float x = acc[nt][v] + ((const float*)&bv)[v];
            x = fmaxf(x, 0.f);
            val[nt][v] = x;
            ss = fmaf(x, x, ss);
        }
    }
    ss += __shfl_xor(ss, 16);
    ss += __shfl_xor(ss, 32);
    float nr = sqrtf(ss);
    nr = (nr == 0.f) ? 1.f : nr;
    float inv = 1.f / nr;

    const int gr = rb + row;
    if (gr < nrows) {
        #pragma unroll
        for (int nt = 0; nt < 8; ++nt) {
            float4 o;
            o.x = val[nt][0] * inv; o.y = val[nt][1] * inv;
            o.z = val[nt][2] * inv; o.w = val[nt][3] * inv;
            *(float4*)&out[(size_t)gr * 128 + nt * 16 + lk * 4] = o;
        }
    }
}

// ---------------------------------------------------------------------------
extern "C" void kernel_launch(void* const* d_in, const int* in_sizes, int n_in,
                              void* d_out, int out_size, void* d_ws, size_t ws_size,
                              hipStream_t stream)
{
    const float* h   = (const float*)d_in[0];
    const float* wts = (const float*)d_in[1];
    const int*   src = (const int*)d_in[2];
    const int*   dst = (const int*)d_in[3];
    const float* qw  = (const float*)d_in[5];
    const float* qb  = (const float*)d_in[6];
    const float* www = (const float*)d_in[7];
    const float* wb  = (const float*)d_in[8];
    float* out = (float*)d_out;

    const int n_src   = in_sizes[0] / 128;
    const int n_edges = in_sizes[1];
    const int n_dst   = out_size / 128;

    const int G  = 128;                           // partition / hist blocks
    const int NB = (n_dst + 31) / 32;             // buckets of 32 dst rows (1563)
    const int NBINS = NB * G;                     // bin table (200064)
    const int nbs = (NBINS + 1023) / 1024;        // 196 (<=256 required)

    // workspace layout (all segment sizes even -> 16B alignment preserved)
    ushort* nbuf    = (ushort*)d_ws;                         // n_src*128 bf16
    ushort* z2      = nbuf + (size_t)n_src * 128;            // n_dst*128 bf16
    ushort* hb      = z2 + (size_t)n_dst * 128;              // n_src*128 bf16
    ushort* qwb     = hb + (size_t)n_src * 128;              // 16384 bf16
    ushort* wwb     = qwb + 16384;                           // 32768 bf16
    int2*   eb      = (int2*)(wwb + 32768);                  // n_edges int2
    int*    hist    = (int*)(eb + n_edges);                  // NBINS
    int*    binoff0 = hist + NBINS;                          // NBINS
    int*    parts   = binoff0 + NBINS;                       // <= 256 (raw totals)

    const int CVT = 768;                          // cvt blocks (one pass w/ hist)
    k_hist_cvt<<<G + CVT, 512, 0, stream>>>(dst, hist, n_edges, NB, G,
                                            h, qw, www, hb, qwb, wwb, n_src);

    k_scan_blk<<<nbs, 1024, 0, stream>>>(hist, binoff0, parts, NBINS);

    const int t1 = (n_src + 127) / 128;           // 782 gemm1 tiles/blocks
    k_part_gemm1<<<G + t1, 512, 0, stream>>>(src, dst, wts, binoff0, parts, eb,
                                             n_edges, NB, nbs, G,
                                             hb, qwb, qb, nbuf, n_src);

    k_bsort_gather<<<NB, 256, 0, stream>>>(nbuf, eb, binoff0, parts, z2,
                                           n_dst, n_edges, G, NB, nbs);

    const int t2 = (n_dst + 127) / 128;
    k_gemm2<<<t2, 512, 0, stream>>>(hb, z2, wwb, wb, out, n_dst);
}